// Round 13
// baseline (925.959 us; speedup 1.0000x reference)
//
#include <hip/hip_runtime.h>
#include <stdint.h>

#define BLOCK 256
#define NB 64              // buckets (clause-space tiles of 65536)
#define FL 64              // LDS staging slots per bucket
#define CAP (1u << 17)     // 131072 u16 entries per global bucket (~1.35x expected)
#define BSHIFT 16          // bucket = cls >> 16  (covers nc <= 64*65536)

typedef int iv4 __attribute__((ext_vector_type(4)));

// ---------------------------------------------------------------------------
// ws layout (offsets computed on host):
//   [0]        hdr: [0]=nsat [1]=done
//   [64]       gcur[NB]  : global bucket cursors
//   [320]      predbits  : 1 bit/var (~125 KB)
//   [satoff]   satmap    : overflow-sink bitmap, NB*8KB = 512 KB (zeroed)
//   [gboff]    gbuckets  : NB * CAP u16 entries (16 MB)
// Everything (re)built every call.
// ---------------------------------------------------------------------------

__global__ void prep(const float* __restrict__ preds,
                     unsigned long long* __restrict__ predbits,
                     uint4* __restrict__ satz,          // satmap as uint4
                     unsigned* __restrict__ hdr,
                     unsigned* __restrict__ gcur,
                     int n_vars) {
    const int gid = blockIdx.x * blockDim.x + threadIdx.x;
    const int stride = gridDim.x * blockDim.x;

    // pack preds -> 1 bit per var
    const int nv64 = (n_vars + 63) & ~63;
    for (int i = gid; i < nv64; i += stride) {
        bool b = false;
        if (i < n_vars) b = (preds[i] >= 0.5f);
        const unsigned long long m = __ballot(b);
        if ((threadIdx.x & 63) == 0) predbits[i >> 6] = m;
    }

    // zero the overflow satmap: NB*2048 words = 32768 uint4
    const uint4 z = {0u, 0u, 0u, 0u};
    for (int i = gid; i < NB * 2048 / 4; i += stride) satz[i] = z;

    if (gid < 2) hdr[gid] = 0u;
    if (gid < NB) gcur[gid] = 0u;
}

__device__ __forceinline__ void edge_one(int lit, int cls, int nv,
                                         const unsigned* __restrict__ predbits,
                                         unsigned* __restrict__ satmap,
                                         unsigned short (*stage)[NB],
                                         unsigned* __restrict__ scnt) {
    const bool pos = lit < nv;
    const int v = pos ? lit : lit - nv;
    const unsigned pb = predbits[v >> 5];
    const bool pbit = ((pb >> (v & 31)) & 1u) != 0u;
    if (pbit == pos) {
        const unsigned b = ((unsigned)cls) >> BSHIFT;
        if (b < NB) {
            const unsigned slot = atomicAdd(&scnt[b], 1u);   // ds_add
            if (slot < FL) {
                stage[slot][b] = (unsigned short)(cls & 0xFFFF);
                return;
            }
        }
        // rare overflow (or cls out of bucket range): direct bitmap OR
        atomicOr(&satmap[((unsigned)cls) >> 5], 1u << (cls & 31));
    }
}

__global__ void phase1(const int* __restrict__ lits,
                       const int* __restrict__ clauses,
                       const unsigned* __restrict__ predbits,
                       unsigned* __restrict__ satmap,
                       unsigned* __restrict__ gcur,
                       unsigned short* __restrict__ gb,
                       int n_edges, int n_vars) {
    __shared__ unsigned short stage[FL][NB];   // [slot][bucket]: conflict-free writes
    __shared__ unsigned scnt[NB];

    for (int t = threadIdx.x; t < NB; t += BLOCK) scnt[t] = 0u;
    __syncthreads();

    const int tid = blockIdx.x * BLOCK + threadIdx.x;
    const int T = gridDim.x * BLOCK;
    const int n4 = n_edges >> 2;

    const iv4* __restrict__ l4 = reinterpret_cast<const iv4*>(lits);
    const iv4* __restrict__ c4 = reinterpret_cast<const iv4*>(clauses);

    int i = tid;
    // 8 independent NT loads issued before any use (sched_barrier pins order)
    for (; i + 3 * T < n4; i += 4 * T) {
        const iv4 L0 = __builtin_nontemporal_load(&l4[i]);
        const iv4 C0 = __builtin_nontemporal_load(&c4[i]);
        const iv4 L1 = __builtin_nontemporal_load(&l4[i + T]);
        const iv4 C1 = __builtin_nontemporal_load(&c4[i + T]);
        const iv4 L2 = __builtin_nontemporal_load(&l4[i + 2 * T]);
        const iv4 C2 = __builtin_nontemporal_load(&c4[i + 2 * T]);
        const iv4 L3 = __builtin_nontemporal_load(&l4[i + 3 * T]);
        const iv4 C3 = __builtin_nontemporal_load(&c4[i + 3 * T]);
        __builtin_amdgcn_sched_barrier(0);
        #pragma unroll
        for (int k = 0; k < 4; ++k) edge_one(L0[k], C0[k], n_vars, predbits, satmap, stage, scnt);
        #pragma unroll
        for (int k = 0; k < 4; ++k) edge_one(L1[k], C1[k], n_vars, predbits, satmap, stage, scnt);
        #pragma unroll
        for (int k = 0; k < 4; ++k) edge_one(L2[k], C2[k], n_vars, predbits, satmap, stage, scnt);
        #pragma unroll
        for (int k = 0; k < 4; ++k) edge_one(L3[k], C3[k], n_vars, predbits, satmap, stage, scnt);
    }
    for (; i < n4; i += T) {
        const iv4 l = __builtin_nontemporal_load(&l4[i]);
        const iv4 c = __builtin_nontemporal_load(&c4[i]);
        #pragma unroll
        for (int k = 0; k < 4; ++k) edge_one(l[k], c[k], n_vars, predbits, satmap, stage, scnt);
    }
    for (int j = (n4 << 2) + tid; j < n_edges; j += T)
        edge_one(lits[j], clauses[j], n_vars, predbits, satmap, stage, scnt);

    __syncthreads();

    // flush staging: wave w handles buckets w, w+4, ... ; coalesced u16 bursts
    const int wid = threadIdx.x >> 6;
    const int lane = threadIdx.x & 63;
    for (int b = wid; b < NB; b += BLOCK / 64) {
        const unsigned n = min(scnt[b], (unsigned)FL);
        unsigned base = 0;
        if (lane == 0 && n) base = atomicAdd(&gcur[b], n);
        base = __shfl(base, 0);
        if (lane < (int)n) {
            const unsigned idx = base + (unsigned)lane;
            const unsigned short e = stage[lane][b];
            if (idx < CAP) {
                gb[(size_t)b * CAP + idx] = e;
            } else {
                const unsigned cls = ((unsigned)b << BSHIFT) | (unsigned)e;
                atomicOr(&satmap[cls >> 5], 1u << (cls & 31));
            }
        }
    }
}

__global__ void phase2(const unsigned short* __restrict__ gb,
                       const unsigned* __restrict__ gcur,
                       const unsigned* __restrict__ satmap,
                       unsigned* __restrict__ nsat,
                       unsigned* __restrict__ done,
                       float* __restrict__ out,
                       const int* __restrict__ nc_p,
                       int n_vars) {
    const int nc = *nc_p;
    const unsigned b = blockIdx.x;
    const unsigned NBdev = ((unsigned)nc + 65535u) >> BSHIFT;

    __shared__ unsigned bm[2048];   // 8 KB = 65536 clause bits
    __shared__ unsigned rsm[BLOCK / 64];
    unsigned blocksum = 0;

    if (b < NBdev && b < NB) {
        for (int w = threadIdx.x; w < 2048; w += BLOCK) bm[w] = 0u;
        __syncthreads();

        const unsigned n = min(gcur[b], CAP);
        const unsigned short* mb = gb + (size_t)b * CAP;
        for (unsigned e = threadIdx.x; e < n; e += BLOCK) {
            const unsigned ent = mb[e];
            atomicOr(&bm[ent >> 5], 1u << (ent & 31));
        }
        __syncthreads();

        unsigned acc = 0;
        for (int w = threadIdx.x; w < 2048; w += BLOCK)
            acc += __popc(bm[w] | satmap[b * 2048 + w]);

        #pragma unroll
        for (int off = 32; off > 0; off >>= 1) acc += __shfl_down(acc, off);
        const int lane = threadIdx.x & 63;
        const int wid  = threadIdx.x >> 6;
        if (lane == 0) rsm[wid] = acc;
        __syncthreads();
        if (threadIdx.x == 0) {
            #pragma unroll
            for (int w = 0; w < BLOCK / 64; ++w) blocksum += rsm[w];
        }
    }

    if (threadIdx.x == 0) {
        atomicAdd(nsat, blocksum);
        __threadfence();
        const unsigned ticket = atomicAdd(done, 1u);
        if (ticket == (unsigned)(gridDim.x - 1)) {
            const unsigned total = atomicAdd(nsat, 0u);
            *out = ((float)nc - (float)total) / (float)n_vars;
        }
    }
}

// ---------------- fallback path (ws too small): measured R12 structure ------
__global__ void scatter_fb(const int* __restrict__ lits,
                           const int* __restrict__ clauses,
                           const unsigned* __restrict__ predbits,
                           unsigned* __restrict__ satmap,
                           int n_edges, int n_vars) {
    const int tid = blockIdx.x * blockDim.x + threadIdx.x;
    const int T = gridDim.x * blockDim.x;
    for (int j = tid; j < n_edges; j += T) {
        const int lit = lits[j];
        const int cls = clauses[j];
        const bool pos = lit < n_vars;
        const int v = pos ? lit : lit - n_vars;
        const unsigned pb = predbits[v >> 5];
        const bool pbit = ((pb >> (v & 31)) & 1u) != 0u;
        if (pbit == pos)
            atomicOr(&satmap[((unsigned)cls) >> 5], 1u << (cls & 31));
    }
}

__global__ void reduce_fb(const uint4* __restrict__ sat16,
                          unsigned* __restrict__ nsat,
                          unsigned* __restrict__ done,
                          float* __restrict__ out,
                          const int* __restrict__ nc_p,
                          int n_vars) {
    const int nc = *nc_p;
    const int n16 = NB * 2048 / 4;
    const int tid = blockIdx.x * blockDim.x + threadIdx.x;
    const int stride = gridDim.x * blockDim.x;
    unsigned acc = 0;
    for (int i = tid; i < n16; i += stride) {
        const uint4 v = sat16[i];
        acc += __popc(v.x) + __popc(v.y) + __popc(v.z) + __popc(v.w);
    }
    #pragma unroll
    for (int off = 32; off > 0; off >>= 1) acc += __shfl_down(acc, off);
    __shared__ unsigned smem[BLOCK / 64];
    const int lane = threadIdx.x & 63;
    const int wid  = threadIdx.x >> 6;
    if (lane == 0) smem[wid] = acc;
    __syncthreads();
    if (threadIdx.x == 0) {
        unsigned bsum = 0;
        #pragma unroll
        for (int w = 0; w < BLOCK / 64; ++w) bsum += smem[w];
        atomicAdd(nsat, bsum);
        __threadfence();
        const unsigned ticket = atomicAdd(done, 1u);
        if (ticket == (unsigned)(gridDim.x - 1)) {
            const unsigned total = atomicAdd(nsat, 0u);
            *out = ((float)nc - (float)total) / (float)n_vars;
        }
    }
}

extern "C" void kernel_launch(void* const* d_in, const int* in_sizes, int n_in,
                              void* d_out, int out_size, void* d_ws, size_t ws_size,
                              hipStream_t stream) {
    const float* preds   = (const float*)d_in[0];
    const int*   lits    = (const int*)d_in[1];
    const int*   clauses = (const int*)d_in[2];
    const int*   nc_p    = (const int*)d_in[4];   // n_clauses (device scalar)
    const int    n_vars  = in_sizes[0];
    const int    n_edges = in_sizes[1];

    float* out = (float*)d_out;
    unsigned char* ws = (unsigned char*)d_ws;

    unsigned* hdr  = (unsigned*)ws;                    // [0]=nsat [1]=done
    unsigned* gcur = (unsigned*)(ws + 64);             // NB cursors
    unsigned long long* predbits = (unsigned long long*)(ws + 320);
    const size_t predbits_bytes = ((size_t)((n_vars + 63) / 64)) * 8;
    size_t satoff = (320 + predbits_bytes + 63) & ~(size_t)63;
    unsigned* satmap = (unsigned*)(ws + satoff);       // NB*8KB overflow bitmap
    size_t gboff = (satoff + (size_t)NB * 2048 * 4 + 63) & ~(size_t)63;
    unsigned short* gb = (unsigned short*)(ws + gboff);
    const size_t need = gboff + (size_t)NB * CAP * 2;

    prep<<<1024, BLOCK, 0, stream>>>(preds, predbits, (uint4*)satmap, hdr,
                                     gcur, n_vars);
    if (ws_size >= need) {
        phase1<<<2048, BLOCK, 0, stream>>>(lits, clauses,
                                           (const unsigned*)predbits, satmap,
                                           gcur, gb, n_edges, n_vars);
        phase2<<<NB, BLOCK, 0, stream>>>(gb, gcur, satmap, hdr, hdr + 1, out,
                                         nc_p, n_vars);
    } else {
        scatter_fb<<<2048, BLOCK, 0, stream>>>(lits, clauses,
                                               (const unsigned*)predbits, satmap,
                                               n_edges, n_vars);
        reduce_fb<<<128, BLOCK, 0, stream>>>((const uint4*)satmap, hdr, hdr + 1,
                                             out, nc_p, n_vars);
    }
}